// Round 12
// baseline (87.151 us; speedup 1.0000x reference)
//
#include <hip/hip_runtime.h>

// Bidirectional NN-MSE via MFMA — R28: identical resubmit of R25/R26/R27
// (none ran: GPUAcquisitionTimeout x3 — broker at capacity; no kernel
// signal). QT=4 (4 query fragments per A-load).
// Unified theory after R19/R22/R24: the loop is BYTES-PER-MFMA bound.
// R13/R19: 1 MB L2->CU per pass @ ~29 B/cyc/CU => 14.8 us (matches R22's
// measured marginal pass; warm L2 same cost => BW not latency). R24 LDS
// dedupe: VMEM/4 but 2x ds_read_b128 @ ~12cyc/unit => LDS-pipe-bound at the
// same ~15 us — two walls, same height, hence the null. Fix: raise
// arithmetic intensity. Each wave now holds 4 B-fragments (128 queries);
// one A-pair (2 KB) feeds 8 MFMAs (256 B/MFMA, was 512): per-CU L2 traffic
// 1 MB -> 512 KB => loop ~7.5 us. R14's QT=4 regression causes fixed:
// QBLK=512 -> 512 blocks = 2/CU, BOTH resident at 8 waves/CU (VGPR ~148:
// 64 acc + 32 bank + 16 zero + 16 bq + 8 a + addr; R19 proved 8 waves/CU
// is non-regressive). No LDS, no barriers, R13's proven MMB asm unchanged.
// Note: fusing QT=4 with the double-pass probe was considered and rejected —
// its confirmed-case dur (~66+15=81) aliases the single-pass null (~81).
// Predict: dur 81.2 -> 73-76; absmax 0; fills unchanged. If null: ablate
// load/MFMA/min3 costs with asm-live stubs (rule #17).
//
//   loss = w * mean_n min_j ||p_n - g_j||^2 + (1-w) * mean_m min_i ||g_m - p_i||^2
//
// d^2 = qq - 2 q.r + rr inside mfma_f32_32x32x16_bf16 (K=16), 2-term bf16
// split per operand (exact bf16xbf16 products; absmax 0 R2-R24).

#define NPTS   16384
#define QBLK   512                // 4 waves x 4 frags x 32 queries (QT=4)
#define QCH    (NPTS / QBLK)      // 32 query chunks
#define SSPLIT 8                  // ref splits
#define RBLK   (NPTS / SSPLIT)    // 2048 refs streamed per block (64 tiles)
#define NB1    (2 * QCH * SSPLIT) // 512 blocks (2 per CU, all resident)

typedef __attribute__((ext_vector_type(8)))  __bf16 bf16x8;
typedef __attribute__((ext_vector_type(16))) float  floatx16;

union frag16 { __bf16 v[16]; uint4 q[2]; };

// One thread per (role, point): builds A-form (ref) and B-form (query)
// fragments. A-form pre-swizzled in MFMA wave order: uint4 index
// (p>>5)*64 + half*32 + (p&31) -> each wave tile read is one contiguous,
// perfectly-coalesced 1 KB global_load_dwordx4 burst.
__global__ __launch_bounds__(256) void prep_kernel(
    const float* __restrict__ pred, const float* __restrict__ gt,
    uint4* __restrict__ aform, uint4* __restrict__ bform,
    float* __restrict__ out)
{
    const int i = blockIdx.x * 256 + threadIdx.x;   // 0 .. 2*NPTS-1
    if (i == 0) out[0] = 0.0f;
    const int role = (i < NPTS) ? 0 : 1;            // 0=pred, 1=gt
    const int p = i - role * NPTS;
    const float* __restrict__ src = role ? gt : pred;

    const float x = src[p * 3 + 0], y = src[p * 3 + 1], z = src[p * 3 + 2];
    const float nn = x * x + y * y + z * z;
    const __bf16 xh = (__bf16)x, yh = (__bf16)y, zh = (__bf16)z;
    const __bf16 xl = (__bf16)(x - (float)xh);
    const __bf16 yl = (__bf16)(y - (float)yh);
    const __bf16 zl = (__bf16)(z - (float)zh);
    const __bf16 nh = (__bf16)nn;
    const __bf16 nl = (__bf16)(nn - (float)nh);
    const __bf16 one = (__bf16)1.0f;

    frag16 A;
    A.v[0]  = (__bf16)(-2.0f * (float)xh); A.v[1]  = A.v[0];
    A.v[2]  = (__bf16)(-2.0f * (float)xl); A.v[3]  = A.v[2];
    A.v[4]  = (__bf16)(-2.0f * (float)yh); A.v[5]  = A.v[4];
    A.v[6]  = (__bf16)(-2.0f * (float)yl); A.v[7]  = A.v[6];
    A.v[8]  = (__bf16)(-2.0f * (float)zh); A.v[9]  = A.v[8];
    A.v[10] = (__bf16)(-2.0f * (float)zl); A.v[11] = A.v[10];
    A.v[12] = nh;  A.v[13] = nl;  A.v[14] = one;  A.v[15] = one;

    frag16 B;
    B.v[0] = xh;  B.v[1]  = xl;  B.v[2]  = xh;  B.v[3]  = xl;
    B.v[4] = yh;  B.v[5]  = yl;  B.v[6]  = yh;  B.v[7]  = yl;
    B.v[8] = zh;  B.v[9]  = zl;  B.v[10] = zh;  B.v[11] = zl;
    B.v[12] = one; B.v[13] = one; B.v[14] = nh;  B.v[15] = nl;

    uint4* da = aform + (size_t)role * (NPTS * 2)
              + ((p >> 5) * 64 + (p & 31));
    da[0]  = A.q[0];        // half 0 (k=0..7)  at +0
    da[32] = A.q[1];        // half 1 (k=8..15) at +32
    uint4* db = bform + (size_t)role * (NPTS * 2) + p * 2;
    db[0] = B.q[0];
    db[1] = B.q[1];
}

// R13's proven asm block: 2 MFMA into fixed dest banks + 16 v_min3 into
// "+v"-pinned accumulators. One emission per query-fragment per tile-pair.
#define MFMA_MIN_BLOCK(BQ, M)                                               \
    asm volatile(                                                           \
        "v_mfma_f32_32x32x16_bf16 v[32:47], %[A0], %[B], %[Z]\n\t"          \
        "v_mfma_f32_32x32x16_bf16 v[48:63], %[A1], %[B], %[Z]\n\t"          \
        "s_nop 7\n\ts_nop 7\n\ts_nop 7\n\ts_nop 7\n\t"                      \
        "v_min3_f32 %[M0],  %[M0],  v32, v48\n\t"                           \
        "v_min3_f32 %[M1],  %[M1],  v33, v49\n\t"                           \
        "v_min3_f32 %[M2],  %[M2],  v34, v50\n\t"                           \
        "v_min3_f32 %[M3],  %[M3],  v35, v51\n\t"                           \
        "v_min3_f32 %[M4],  %[M4],  v36, v52\n\t"                           \
        "v_min3_f32 %[M5],  %[M5],  v37, v53\n\t"                           \
        "v_min3_f32 %[M6],  %[M6],  v38, v54\n\t"                           \
        "v_min3_f32 %[M7],  %[M7],  v39, v55\n\t"                           \
        "v_min3_f32 %[M8],  %[M8],  v40, v56\n\t"                           \
        "v_min3_f32 %[M9],  %[M9],  v41, v57\n\t"                           \
        "v_min3_f32 %[M10], %[M10], v42, v58\n\t"                           \
        "v_min3_f32 %[M11], %[M11], v43, v59\n\t"                           \
        "v_min3_f32 %[M12], %[M12], v44, v60\n\t"                           \
        "v_min3_f32 %[M13], %[M13], v45, v61\n\t"                           \
        "v_min3_f32 %[M14], %[M14], v46, v62\n\t"                           \
        "v_min3_f32 %[M15], %[M15], v47, v63"                               \
        : [M0] "+v"(M[0]),  [M1] "+v"(M[1]),  [M2] "+v"(M[2]),              \
          [M3] "+v"(M[3]),  [M4] "+v"(M[4]),  [M5] "+v"(M[5]),              \
          [M6] "+v"(M[6]),  [M7] "+v"(M[7]),  [M8] "+v"(M[8]),              \
          [M9] "+v"(M[9]),  [M10] "+v"(M[10]), [M11] "+v"(M[11]),           \
          [M12] "+v"(M[12]), [M13] "+v"(M[13]), [M14] "+v"(M[14]),          \
          [M15] "+v"(M[15])                                                 \
        : [A0] "v"(a0), [A1] "v"(a1), [B] "v"(BQ), [Z] "v"(zero)            \
        : "v32", "v33", "v34", "v35", "v36", "v37", "v38", "v39",           \
          "v40", "v41", "v42", "v43", "v44", "v45", "v46", "v47",           \
          "v48", "v49", "v50", "v51", "v52", "v53", "v54", "v55",           \
          "v56", "v57", "v58", "v59", "v60", "v61", "v62", "v63")

__global__ __launch_bounds__(256) void nn_part_kernel(
    const uint4* __restrict__ aform, const uint4* __restrict__ bform,
    float* __restrict__ partial)
{
    const int bx   = blockIdx.x;           // 0..NB1-1
    const int dir  = bx >> 8;              // 0: Q=pred,R=gt ; 1: Q=gt,R=pred
    const int qc   = (bx >> 3) & 31;       // 0..31
    const int s    = bx & 7;               // 0..7
    const int tid  = threadIdx.x;
    const int lane = tid & 63;
    const int wave = tid >> 6;
    const int lid  = lane & 31;
    const int half = lane >> 5;

    // dir 0: queries=pred(role 0), refs=gt(role 1); dir 1 swapped
    const uint4* __restrict__ Aref = aform + (size_t)(dir ? 0 : 1) * (NPTS * 2);
    const uint4* __restrict__ Bqry = bform + (size_t)(dir ? 1 : 0) * (NPTS * 2);

    // ---- four query B-fragments per wave (prebuilt, 16 B/lane each) ----
    const int qbase = qc * QBLK + wave * 128;
    const bf16x8 bq0 = __builtin_bit_cast(bf16x8, Bqry[(qbase +  0 + lid) * 2 + half]);
    const bf16x8 bq1 = __builtin_bit_cast(bf16x8, Bqry[(qbase + 32 + lid) * 2 + half]);
    const bf16x8 bq2 = __builtin_bit_cast(bf16x8, Bqry[(qbase + 64 + lid) * 2 + half]);
    const bf16x8 bq3 = __builtin_bit_cast(bf16x8, Bqry[(qbase + 96 + lid) * 2 + half]);

    floatx16 zero;
#pragma unroll
    for (int k = 0; k < 16; ++k) zero[k] = 0.0f;

    float ma[16], mb[16], mc[16], md[16];
#pragma unroll
    for (int k = 0; k < 16; ++k) {
        ma[k] = 3.4e38f; mb[k] = 3.4e38f; mc[k] = 3.4e38f; md[k] = 3.4e38f;
    }

    // ---- hot loop: 2 KB A-stream feeds 8 MFMAs (256 B/MFMA) ----
    const uint4* gp = Aref + (size_t)s * (RBLK * 2) + half * 32 + lid;
#pragma unroll 2
    for (int t = 0; t < RBLK / 32; t += 2) {
        const bf16x8 a0 = __builtin_bit_cast(bf16x8, gp[t * 64]);
        const bf16x8 a1 = __builtin_bit_cast(bf16x8, gp[t * 64 + 64]);
        MFMA_MIN_BLOCK(bq0, ma);
        MFMA_MIN_BLOCK(bq1, mb);
        MFMA_MIN_BLOCK(bq2, mc);
        MFMA_MIN_BLOCK(bq3, md);
    }

    // ---- tail: in-lane trees + one shuffle each, plain coalesced store ----
    float* pout = partial + ((size_t)((dir * QCH + qc) * SSPLIT + s)) * QBLK
                + wave * 128;
#define TAIL(M, OFF)                                                        \
    {                                                                       \
        float a = fminf(fminf(M[0], M[1]), fminf(M[2], M[3]));              \
        float b = fminf(fminf(M[4], M[5]), fminf(M[6], M[7]));              \
        float c = fminf(fminf(M[8], M[9]), fminf(M[10], M[11]));            \
        float d = fminf(fminf(M[12], M[13]), fminf(M[14], M[15]));          \
        float v = fminf(fminf(a, b), fminf(c, d));                          \
        v = fminf(v, __shfl_xor(v, 32));                                    \
        if (half == 0) pout[(OFF) + lid] = v;                               \
    }
    TAIL(ma, 0)
    TAIL(mb, 32)
    TAIL(mc, 64)
    TAIL(md, 96)
#undef TAIL
}

// Combine: min over the SSPLIT ref-splits per query, weighted sum into out.
// 128 blocks x 256 threads cover 2 dirs x 32 qc x 512 queries.
__global__ __launch_bounds__(256) void nn_combine_kernel(
    const float* __restrict__ partial, const float* __restrict__ weight,
    float* __restrict__ out)
{
    const int b   = blockIdx.x;        // 0..127
    const int dir = b >> 6;            // 0..1
    const int sub = b & 63;            // 0..63
    const int qc  = sub >> 1;          // 0..31
    const int hs  = sub & 1;           // which 256-half of the 512 queries
    const int t   = threadIdx.x;

    const float* p = partial + ((size_t)((dir * QCH + qc) * SSPLIT)) * QBLK
                   + hs * 256;
    float v = p[t];
#pragma unroll
    for (int s = 1; s < SSPLIT; ++s)
        v = fminf(v, p[(size_t)s * QBLK + t]);

    for (int off = 32; off; off >>= 1) v += __shfl_down(v, off);
    __shared__ float ws[4];
    if ((t & 63) == 0) ws[t >> 6] = v;
    __syncthreads();
    if (t == 0) {
        const float sum = ws[0] + ws[1] + ws[2] + ws[3];
        const float wgt = weight[0];
        const float scale = (dir ? (1.0f - wgt) : wgt) / (3.0f * (float)NPTS);
        atomicAdd(out, sum * scale);
    }
}

extern "C" void kernel_launch(void* const* d_in, const int* in_sizes, int n_in,
                              void* d_out, int out_size, void* d_ws, size_t ws_size,
                              hipStream_t stream) {
    const float* pred   = (const float*)d_in[0];
    const float* gt     = (const float*)d_in[1];
    const float* weight = (const float*)d_in[2];

    // ws: [partial 512 KB][aform 1 MB][bform 1 MB]
    float* partial = (float*)d_ws;                       // 2*QCH*SSPLIT*QBLK f32
    uint4* aform = (uint4*)((char*)d_ws + (size_t)2 * QCH * SSPLIT * QBLK * 4);
    uint4* bform = aform + (size_t)2 * NPTS * 2;

    prep_kernel<<<2 * NPTS / 256, 256, 0, stream>>>(pred, gt, aform, bform,
                                                    (float*)d_out);
    nn_part_kernel<<<NB1, 256, 0, stream>>>(aform, bform, partial);
    nn_combine_kernel<<<2 * QCH * (QBLK / 256), 256, 0, stream>>>(
        partial, weight, (float*)d_out);
}

// Round 14
// 83.395 us; speedup vs baseline: 1.0450x; 1.0450x over previous
//
#include <hip/hip_runtime.h>

// Bidirectional NN-MSE via MFMA — R30: identical resubmit of R29 (never ran:
// GPUAcquisitionTimeout — broker at capacity; no kernel signal). v_perm
// expansion re-audited byte-level: bit-identical fragments guaranteed.
// Packed A-form (2x traffic cut) at UNCHANGED R13 geometry.
// R28 post-mortem: QT=4 regressed (87.2 vs 81.2) but was CONFOUNDED —
// ~146 VGPR > 128 cliff => 2 waves/SIMD vs R13's 4. Loop cost tracks
// occupancy x per-wave stall; traffic effect untested at fixed occupancy
// (R24's LDS dedupe swapped walls; R19 ILP null; R28 paid the cliff).
// This probe: A-form stores every value DUPLICATED (v0=v1 etc) => only 8
// unique bf16/pt. Pack to 16 B/pt (8 B/lane/tile, dwordx2 loads), expand
// in-register to the BIT-IDENTICAL fragment: 4 v_perm_b32 + 2 selects per
// tile (~24 cyc VALU/unit). VGPR ~+6 => ~115 <= 128: occupancy preserved
// at 4 waves/SIMD, 1024 blocks, MMB asm unchanged, absmax 0 by
// construction. Per-CU L2 traffic 1 MB -> 512 KB/pass.
// Pre-committed: L2-BW-bound => loop ~8us, dur 73-75. Null (80.5-82) =>
// BW falsified at fixed occupancy; loop structural (wave-serial MFMA->min3
// at VGPR-capped occupancy) => state roofline arithmetic next. Regression
// (>83) => expansion VALU cost > BW gain; revert.
//
//   loss = w * mean_n min_j ||p_n - g_j||^2 + (1-w) * mean_m min_i ||g_m - p_i||^2
//
// d^2 = qq - 2 q.r + rr inside mfma_f32_32x32x16_bf16 (K=16), 2-term bf16
// split per operand (exact bf16xbf16 products; absmax 0 R2-R28).

#define NPTS   16384
#define QBLK   256                // 4 waves x 2 frags x 32 queries (QT=2)
#define QCH    (NPTS / QBLK)      // 64 query chunks
#define SSPLIT 8                  // ref splits
#define RBLK   (NPTS / SSPLIT)    // 2048 refs streamed per block (64 tiles)
#define NB1    (2 * QCH * SSPLIT) // 1024 blocks (4/CU, 16 waves/CU)

typedef __attribute__((ext_vector_type(8)))  __bf16 bf16x8;
typedef __attribute__((ext_vector_type(16))) float  floatx16;

union frag16 { __bf16 v[16]; uint4 q[2]; };
union pack8  { __bf16 v[8];  uint2 q[2]; };

// One thread per (role, point). A-side now PACKED: 8 unique bf16/pt
// [m2xh,m2xl,m2yh,m2yl | m2zh,m2zl,nh,nl] as two uint2 at the same
// wave-order swizzle (p>>5)*64 + half*32 + (p&31) -> per-tile reads are
// one contiguous 512 B dwordx2 burst per half. B-form unchanged.
__global__ __launch_bounds__(256) void prep_kernel(
    const float* __restrict__ pred, const float* __restrict__ gt,
    uint2* __restrict__ pform, uint4* __restrict__ bform,
    float* __restrict__ out)
{
    const int i = blockIdx.x * 256 + threadIdx.x;   // 0 .. 2*NPTS-1
    if (i == 0) out[0] = 0.0f;
    const int role = (i < NPTS) ? 0 : 1;            // 0=pred, 1=gt
    const int p = i - role * NPTS;
    const float* __restrict__ src = role ? gt : pred;

    const float x = src[p * 3 + 0], y = src[p * 3 + 1], z = src[p * 3 + 2];
    const float nn = x * x + y * y + z * z;
    const __bf16 xh = (__bf16)x, yh = (__bf16)y, zh = (__bf16)z;
    const __bf16 xl = (__bf16)(x - (float)xh);
    const __bf16 yl = (__bf16)(y - (float)yh);
    const __bf16 zl = (__bf16)(z - (float)zh);
    const __bf16 nh = (__bf16)nn;
    const __bf16 nl = (__bf16)(nn - (float)nh);
    const __bf16 one = (__bf16)1.0f;

    pack8 P;
    P.v[0] = (__bf16)(-2.0f * (float)xh);
    P.v[1] = (__bf16)(-2.0f * (float)xl);
    P.v[2] = (__bf16)(-2.0f * (float)yh);
    P.v[3] = (__bf16)(-2.0f * (float)yl);
    P.v[4] = (__bf16)(-2.0f * (float)zh);
    P.v[5] = (__bf16)(-2.0f * (float)zl);
    P.v[6] = nh;
    P.v[7] = nl;

    frag16 B;
    B.v[0] = xh;  B.v[1]  = xl;  B.v[2]  = xh;  B.v[3]  = xl;
    B.v[4] = yh;  B.v[5]  = yl;  B.v[6]  = yh;  B.v[7]  = yl;
    B.v[8] = zh;  B.v[9]  = zl;  B.v[10] = zh;  B.v[11] = zl;
    B.v[12] = one; B.v[13] = one; B.v[14] = nh;  B.v[15] = nl;

    uint2* dp = pform + (size_t)role * (NPTS * 2)
              + ((p >> 5) * 64 + (p & 31));
    dp[0]  = P.q[0];        // half 0 source (k=0..7 after expand)
    dp[32] = P.q[1];        // half 1 source (k=8..15 after expand)
    uint4* db = bform + (size_t)role * (NPTS * 2) + p * 2;
    db[0] = B.q[0];
    db[1] = B.q[1];
}

// Expand packed uint2 -> bit-identical A-fragment for this lane's half.
// v_perm_b32 selector bytes 0-3 index the LOW source word (little-endian):
// half 0 (p=(p0,p1)): {dup_lo(p0), dup_hi(p0), dup_lo(p1), dup_hi(p1)}
//   = (m2xh,m2xh)(m2xl,m2xl)(m2yh,m2yh)(m2yl,m2yl)
// half 1 (p=(p2,p3)): {dup_lo(p2), dup_hi(p2), p3, (1,1)}
//   = (m2zh,m2zh)(m2zl,m2zl)(nh,nl)(1.0,1.0)
__device__ __forceinline__ bf16x8 expand_a(uint2 p, int half) {
    const unsigned SEL_LO = 0x01000100u;   // bytes {0,1,0,1}
    const unsigned SEL_HI = 0x03020302u;   // bytes {2,3,2,3}
    const unsigned ONE2   = 0x3F803F80u;   // bf16 (1.0,1.0)
    uint4 f;
    f.x = __builtin_amdgcn_perm(p.x, p.x, SEL_LO);
    f.y = __builtin_amdgcn_perm(p.x, p.x, SEL_HI);
    f.z = half ? p.y : __builtin_amdgcn_perm(p.y, p.y, SEL_LO);
    f.w = half ? ONE2 : __builtin_amdgcn_perm(p.y, p.y, SEL_HI);
    return __builtin_bit_cast(bf16x8, f);
}

// R13's proven asm block: 2 MFMA into fixed dest banks + 16 v_min3 into
// "+v"-pinned accumulators. One emission per query-fragment per tile-pair.
#define MFMA_MIN_BLOCK(BQ, M)                                               \
    asm volatile(                                                           \
        "v_mfma_f32_32x32x16_bf16 v[32:47], %[A0], %[B], %[Z]\n\t"          \
        "v_mfma_f32_32x32x16_bf16 v[48:63], %[A1], %[B], %[Z]\n\t"          \
        "s_nop 7\n\ts_nop 7\n\ts_nop 7\n\ts_nop 7\n\t"                      \
        "v_min3_f32 %[M0],  %[M0],  v32, v48\n\t"                           \
        "v_min3_f32 %[M1],  %[M1],  v33, v49\n\t"                           \
        "v_min3_f32 %[M2],  %[M2],  v34, v50\n\t"                           \
        "v_min3_f32 %[M3],  %[M3],  v35, v51\n\t"                           \
        "v_min3_f32 %[M4],  %[M4],  v36, v52\n\t"                           \
        "v_min3_f32 %[M5],  %[M5],  v37, v53\n\t"                           \
        "v_min3_f32 %[M6],  %[M6],  v38, v54\n\t"                           \
        "v_min3_f32 %[M7],  %[M7],  v39, v55\n\t"                           \
        "v_min3_f32 %[M8],  %[M8],  v40, v56\n\t"                           \
        "v_min3_f32 %[M9],  %[M9],  v41, v57\n\t"                           \
        "v_min3_f32 %[M10], %[M10], v42, v58\n\t"                           \
        "v_min3_f32 %[M11], %[M11], v43, v59\n\t"                           \
        "v_min3_f32 %[M12], %[M12], v44, v60\n\t"                           \
        "v_min3_f32 %[M13], %[M13], v45, v61\n\t"                           \
        "v_min3_f32 %[M14], %[M14], v46, v62\n\t"                           \
        "v_min3_f32 %[M15], %[M15], v47, v63"                               \
        : [M0] "+v"(M[0]),  [M1] "+v"(M[1]),  [M2] "+v"(M[2]),              \
          [M3] "+v"(M[3]),  [M4] "+v"(M[4]),  [M5] "+v"(M[5]),              \
          [M6] "+v"(M[6]),  [M7] "+v"(M[7]),  [M8] "+v"(M[8]),              \
          [M9] "+v"(M[9]),  [M10] "+v"(M[10]), [M11] "+v"(M[11]),           \
          [M12] "+v"(M[12]), [M13] "+v"(M[13]), [M14] "+v"(M[14]),          \
          [M15] "+v"(M[15])                                                 \
        : [A0] "v"(a0), [A1] "v"(a1), [B] "v"(BQ), [Z] "v"(zero)            \
        : "v32", "v33", "v34", "v35", "v36", "v37", "v38", "v39",           \
          "v40", "v41", "v42", "v43", "v44", "v45", "v46", "v47",           \
          "v48", "v49", "v50", "v51", "v52", "v53", "v54", "v55",           \
          "v56", "v57", "v58", "v59", "v60", "v61", "v62", "v63")

__global__ __launch_bounds__(256) void nn_part_kernel(
    const uint2* __restrict__ pform, const uint4* __restrict__ bform,
    float* __restrict__ partial)
{
    const int bx   = blockIdx.x;           // 0..NB1-1
    const int dir  = bx >> 9;              // 0: Q=pred,R=gt ; 1: Q=gt,R=pred
    const int qc   = (bx & 511) >> 3;      // 0..63
    const int s    = bx & 7;               // 0..7
    const int tid  = threadIdx.x;
    const int lane = tid & 63;
    const int wave = tid >> 6;
    const int lid  = lane & 31;
    const int half = lane >> 5;

    // dir 0: queries=pred(role 0), refs=gt(role 1); dir 1 swapped
    const uint2* __restrict__ Pref = pform + (size_t)(dir ? 0 : 1) * (NPTS * 2);
    const uint4* __restrict__ Bqry = bform + (size_t)(dir ? 1 : 0) * (NPTS * 2);

    // ---- two query B-fragments per wave (prebuilt, 16 B/lane) ----
    const int qbase = qc * QBLK + wave * 64;
    const bf16x8 bq0 = __builtin_bit_cast(bf16x8, Bqry[(qbase + lid) * 2 + half]);
    const bf16x8 bq1 = __builtin_bit_cast(bf16x8, Bqry[(qbase + 32 + lid) * 2 + half]);

    floatx16 zero;
#pragma unroll
    for (int k = 0; k < 16; ++k) zero[k] = 0.0f;

    float ma[16], mb[16];
#pragma unroll
    for (int k = 0; k < 16; ++k) { ma[k] = 3.4e38f; mb[k] = 3.4e38f; }

    // ---- hot loop: 1 KB packed A-stream + in-reg expand feeds 4 MFMAs ----
    const uint2* gp = Pref + (size_t)s * (RBLK * 2) + half * 32 + lid;
#pragma unroll 2
    for (int t = 0; t < RBLK / 32; t += 2) {
        const uint2 p0 = gp[t * 64];
        const uint2 p1 = gp[t * 64 + 64];
        const bf16x8 a0 = expand_a(p0, half);
        const bf16x8 a1 = expand_a(p1, half);
        MFMA_MIN_BLOCK(bq0, ma);
        MFMA_MIN_BLOCK(bq1, mb);
    }

    // ---- tail: in-lane trees + one shuffle each, plain coalesced store ----
    float* pout = partial + ((size_t)((dir * QCH + qc) * SSPLIT + s)) * QBLK
                + wave * 64;
    {
        float a = fminf(fminf(ma[0], ma[1]), fminf(ma[2], ma[3]));
        float b = fminf(fminf(ma[4], ma[5]), fminf(ma[6], ma[7]));
        float c = fminf(fminf(ma[8], ma[9]), fminf(ma[10], ma[11]));
        float d = fminf(fminf(ma[12], ma[13]), fminf(ma[14], ma[15]));
        float v = fminf(fminf(a, b), fminf(c, d));
        v = fminf(v, __shfl_xor(v, 32));
        if (half == 0) pout[lid] = v;
    }
    {
        float a = fminf(fminf(mb[0], mb[1]), fminf(mb[2], mb[3]));
        float b = fminf(fminf(mb[4], mb[5]), fminf(mb[6], mb[7]));
        float c = fminf(fminf(mb[8], mb[9]), fminf(mb[10], mb[11]));
        float d = fminf(fminf(mb[12], mb[13]), fminf(mb[14], mb[15]));
        float v = fminf(fminf(a, b), fminf(c, d));
        v = fminf(v, __shfl_xor(v, 32));
        if (half == 0) pout[32 + lid] = v;
    }
}

// Combine: min over the SSPLIT ref-splits per query, weighted sum into out.
__global__ __launch_bounds__(256) void nn_combine_kernel(
    const float* __restrict__ partial, const float* __restrict__ weight,
    float* __restrict__ out)
{
    const int b   = blockIdx.x;        // 0..127 : dir = b>>6, qc = b&63
    const int dir = b >> 6;
    const int qc  = b & 63;
    const int t   = threadIdx.x;

    const float* p = partial + ((size_t)((dir * QCH + qc) * SSPLIT)) * QBLK;
    float v = p[t];
#pragma unroll
    for (int s = 1; s < SSPLIT; ++s)
        v = fminf(v, p[s * QBLK + t]);

    for (int off = 32; off; off >>= 1) v += __shfl_down(v, off);
    __shared__ float ws[4];
    if ((t & 63) == 0) ws[t >> 6] = v;
    __syncthreads();
    if (t == 0) {
        const float sum = ws[0] + ws[1] + ws[2] + ws[3];
        const float wgt = weight[0];
        const float scale = (dir ? (1.0f - wgt) : wgt) / (3.0f * (float)NPTS);
        atomicAdd(out, sum * scale);
    }
}

extern "C" void kernel_launch(void* const* d_in, const int* in_sizes, int n_in,
                              void* d_out, int out_size, void* d_ws, size_t ws_size,
                              hipStream_t stream) {
    const float* pred   = (const float*)d_in[0];
    const float* gt     = (const float*)d_in[1];
    const float* weight = (const float*)d_in[2];

    // ws: [partial 1 MB][pform 512 KB][bform 1 MB]
    float* partial = (float*)d_ws;                       // 2*QCH*SSPLIT*QBLK f32
    uint2* pform = (uint2*)((char*)d_ws + (size_t)2 * QCH * SSPLIT * QBLK * 4);
    uint4* bform = (uint4*)(pform + (size_t)2 * NPTS * 2);

    prep_kernel<<<2 * NPTS / 256, 256, 0, stream>>>(pred, gt, pform, bform,
                                                    (float*)d_out);
    nn_part_kernel<<<NB1, 256, 0, stream>>>(pform, bform, partial);
    nn_combine_kernel<<<2 * QCH, 256, 0, stream>>>(partial, weight, (float*)d_out);
}